// Round 4
// baseline (783.760 us; speedup 1.0000x reference)
//
#include <hip/hip_runtime.h>
#include <hip/hip_bf16.h>
#include <math.h>

#define N_NODES 100000
#define N_EDGESC 100000
#define NNZ_C   3200000
#define D_IN    512
#define D_HID   16
#define N_CLS   7
#define NBK     782   // ceil(100000/128) node buckets, bucket = v>>7

// ---------------- setup: eoff from sorted eidx ----------------
__global__ void eoff_kernel(const int* __restrict__ eidx, int* __restrict__ eoff, int nnz, int E) {
  int i = blockIdx.x * blockDim.x + threadIdx.x;
  if (i >= nnz) return;
  int ec = eidx[i];
  int ep = (i == 0) ? -1 : eidx[i - 1];
  for (int e = ep + 1; e <= ec; ++e) eoff[e] = i;
  if (i == nnz - 1) {
    for (int e = ec + 1; e <= E; ++e) eoff[e] = nnz;
  }
}

// ---------------- setup: bucket histogram (LDS-staged) ----------------
__global__ void hist_kernel(const int* __restrict__ nidx, int* __restrict__ gcnt, int nnz) {
  __shared__ int lh[NBK];
  int t = threadIdx.x;
  for (int i = t; i < NBK; i += 256) lh[i] = 0;
  __syncthreads();
  int base = blockIdx.x * 12800;
  for (int it = 0; it < 50; ++it) {
    int i = base + it * 256 + t;
    if (i < nnz) atomicAdd(&lh[nidx[i] >> 7], 1);
  }
  __syncthreads();
  for (int i = t; i < NBK; i += 256) {
    int c = lh[i];
    if (c) atomicAdd(&gcnt[i], c);
  }
}

// ---------------- setup: scan bucket counts -> boff, init bcur ----------------
__global__ void bscan_kernel(const int* __restrict__ gcnt, int* __restrict__ boff,
                             int* __restrict__ bcur) {
  __shared__ int lds[1024];
  int t = threadIdx.x;
  int v = (t < NBK) ? gcnt[t] : 0;
  lds[t] = v;
  __syncthreads();
  for (int d = 1; d < 1024; d <<= 1) {
    int u = (t >= d) ? lds[t - d] : 0;
    __syncthreads();
    lds[t] += u;
    __syncthreads();
  }
  if (t < NBK) {
    boff[t + 1] = lds[t];
    bcur[t] = lds[t] - v;   // exclusive
  }
  if (t == 0) boff[0] = 0;
}

// ---------------- setup: bin entries (packed e | (v&127)<<20) per bucket ----------------
__global__ void bin_kernel(const int* __restrict__ nidx, const int* __restrict__ eidx,
                           int* __restrict__ bcur, int* __restrict__ binned, int nnz) {
  __shared__ int lh[NBK];
  __shared__ int gb[NBK];
  int t = threadIdx.x;
  for (int i = t; i < NBK; i += 256) lh[i] = 0;
  __syncthreads();
  int base = blockIdx.x * 12800;
  for (int it = 0; it < 50; ++it) {
    int i = base + it * 256 + t;
    if (i < nnz) atomicAdd(&lh[nidx[i] >> 7], 1);
  }
  __syncthreads();
  for (int i = t; i < NBK; i += 256) {
    int c = lh[i];
    gb[i] = c ? atomicAdd(&bcur[i], c) : 0;
    lh[i] = 0;
  }
  __syncthreads();
  for (int it = 0; it < 50; ++it) {
    int i = base + it * 256 + t;
    if (i < nnz) {
      int v = nidx[i], e = eidx[i];
      int bk = v >> 7;
      int r = atomicAdd(&lh[bk], 1);
      binned[gb[bk] + r] = e | ((v & 127) << 20);
    }
  }
}

// ---------------- setup: per-bucket node-CSR (noff + perm_e) ----------------
__global__ void csr_kernel(const int* __restrict__ binned, const int* __restrict__ boff,
                           int* __restrict__ noff, int* __restrict__ perm_e, int N) {
  __shared__ int lh[128];
  __shared__ int lsc[128];
  __shared__ int lcur[128];
  int b = blockIdx.x;
  int t = threadIdx.x;
  int s = boff[b], e = boff[b + 1];
  if (t < 128) lh[t] = 0;
  __syncthreads();
  for (int i = s + t; i < e; i += 256) {
    atomicAdd(&lh[binned[i] >> 20], 1);
  }
  __syncthreads();
  if (t < 128) lsc[t] = lh[t];
  __syncthreads();
  for (int d = 1; d < 128; d <<= 1) {
    int u = (t < 128 && t >= d) ? lsc[t - d] : 0;
    __syncthreads();
    if (t < 128) lsc[t] += u;
    __syncthreads();
  }
  if (t < 128) {
    int excl = lsc[t] - lh[t];
    lcur[t] = excl;
    int n = b * 128 + t;
    if (n <= N) noff[n] = s + excl;
  }
  __syncthreads();
  for (int i = s + t; i < e; i += 256) {
    int p = binned[i];
    int r = atomicAdd(&lcur[p >> 20], 1);
    perm_e[s + r] = p & 0xFFFFF;
  }
}

// ---------------- GEMM1: h = X[100000,512] @ W[512,16]  (+ phv epilogue) ----------------
// 1 wave/block, lane-per-row (64 rows/wave). W read via wave-uniform (SGPR) loads.
// X staged through XOR-swizzled LDS (pure transpose buffer, conflict-free both ways).
// Chunk c+1 global loads issued before computing chunk c; no barriers (single wave).
__global__ __launch_bounds__(64) void gemm1_kernel(
    const float* __restrict__ X, const float* __restrict__ W,
    const float* __restrict__ a1, const float* __restrict__ a2,
    float* __restrict__ Hout, float2* __restrict__ phv, int N) {
  __shared__ float Xs[64 * 32];
  int lane = threadIdx.x;          // 0..63 = row within tile
  int rowbase = blockIdx.x * 64;
  float acc[16];
#pragma unroll
  for (int j = 0; j < 16; ++j) acc[j] = 0.f;

  float4 pf[8];
#pragma unroll
  for (int it = 0; it < 8; ++it) {
    int idx = it * 64 + lane;
    int r = idx >> 3, f = idx & 7;
    int grow = rowbase + r;
    pf[it] = (grow < N) ? *(const float4*)(X + (size_t)grow * D_IN + f * 4)
                        : make_float4(0.f, 0.f, 0.f, 0.f);
  }

  for (int kc = 0; kc < D_IN; kc += 32) {
    // commit prefetched chunk to LDS (swizzled: col^4*(row&7), pitch 32)
#pragma unroll
    for (int it = 0; it < 8; ++it) {
      int idx = it * 64 + lane;
      int r = idx >> 3, f = idx & 7;
      *(float4*)(Xs + r * 32 + ((4 * f) ^ (4 * (r & 7)))) = pf[it];
    }
    // issue next chunk's global loads
    if (kc + 32 < D_IN) {
      int kn = kc + 32;
#pragma unroll
      for (int it = 0; it < 8; ++it) {
        int idx = it * 64 + lane;
        int r = idx >> 3, f = idx & 7;
        int grow = rowbase + r;
        pf[it] = (grow < N) ? *(const float4*)(X + (size_t)grow * D_IN + kn + f * 4)
                            : make_float4(0.f, 0.f, 0.f, 0.f);
      }
    }
    // compute: lane's row, 32 k; W via uniform loads (scalarized)
    for (int kb = 0; kb < 8; ++kb) {
      float4 xv = *(const float4*)(Xs + lane * 32 + ((4 * kb) ^ (4 * (lane & 7))));
      const float* wr = W + (kc + kb * 4) * 16;
      float xk[4] = {xv.x, xv.y, xv.z, xv.w};
#pragma unroll
      for (int k4 = 0; k4 < 4; ++k4) {
#pragma unroll
        for (int j = 0; j < 16; ++j)
          acc[j] = fmaf(xk[k4], wr[k4 * 16 + j], acc[j]);
      }
    }
  }

  int grow = rowbase + lane;
  float p1 = 0.f, p2 = 0.f;
#pragma unroll
  for (int j = 0; j < 16; ++j) { p1 += acc[j] * a1[j]; p2 += acc[j] * a2[j]; }
  if (grow < N) {
    float4* dst = (float4*)(Hout + (size_t)grow * 16);
    dst[0] = make_float4(acc[0], acc[1], acc[2], acc[3]);
    dst[1] = make_float4(acc[4], acc[5], acc[6], acc[7]);
    dst[2] = make_float4(acc[8], acc[9], acc[10], acc[11]);
    dst[3] = make_float4(acc[12], acc[13], acc[14], acc[15]);
    phv[grow] = make_float2(p1, p2);
  }
}

// ---------------- GEMM2: h2 = elu(H1)[100000,16] @ W2[16,7] (+ phv epilogue) ----------------
__global__ void gemm2_kernel(const float* __restrict__ H1, const float* __restrict__ W2,
                             const float* __restrict__ a1, const float* __restrict__ a2,
                             float* __restrict__ h2, float2* __restrict__ phv, int N) {
  __shared__ float w[D_HID * N_CLS];
  if (threadIdx.x < D_HID * N_CLS) w[threadIdx.x] = W2[threadIdx.x];
  __syncthreads();
  int v = blockIdx.x * blockDim.x + threadIdx.x;
  if (v >= N) return;
  const float4* h4 = (const float4*)(H1 + (size_t)v * D_HID);
  float x[16];
#pragma unroll
  for (int q = 0; q < 4; ++q) {
    float4 f = h4[q];
    x[q * 4 + 0] = f.x; x[q * 4 + 1] = f.y; x[q * 4 + 2] = f.z; x[q * 4 + 3] = f.w;
  }
#pragma unroll
  for (int k = 0; k < 16; ++k) x[k] = x[k] > 0.f ? x[k] : expm1f(x[k]);
  float p1 = 0.f, p2 = 0.f;
#pragma unroll
  for (int jj = 0; jj < N_CLS; ++jj) {
    float acc = 0.f;
#pragma unroll
    for (int k = 0; k < 16; ++k) acc += x[k] * w[k * N_CLS + jj];
    h2[(size_t)v * N_CLS + jj] = acc;
    p1 += acc * a1[jj];
    p2 += acc * a2[jj];
  }
  phv[v] = make_float2(p1, p2);
}

// ---------------- edge phase ----------------
template <int D, int GROUP>
__global__ void edge_phase(const float* __restrict__ h, const float2* __restrict__ phv,
                           const float* __restrict__ a2,
                           const int* __restrict__ eoff, const int* __restrict__ nidx,
                           float* __restrict__ eout, float* __restrict__ pe, int E) {
  constexpr int NG = 64 / GROUP;
  int wave = (blockIdx.x * blockDim.x + threadIdx.x) >> 6;
  int lane = threadIdx.x & 63;
  if (wave >= E) return;
  int o0 = eoff[wave], o1 = eoff[wave + 1];
  int g = lane / GROUP, t = lane % GROUP;
  if (o0 == o1) {
    if (g == 0 && t < D) eout[(size_t)wave * D + t] = 0.f;
    if (lane == 0) pe[wave] = 0.f;
    return;
  }
  float m = -1e30f, l = 0.f;
  for (int i = o0 + lane; i < o1; i += 64) {
    float p = phv[nidx[i]].x;
    float s = p > 0.f ? p : 0.2f * p;
    float mn = fmaxf(m, s);
    l = l * __expf(m - mn) + __expf(s - mn);
    m = mn;
  }
#pragma unroll
  for (int d = 1; d < 64; d <<= 1) {
    float mo = __shfl_xor(m, d), lo = __shfl_xor(l, d);
    float mn = fmaxf(m, mo);
    l = l * __expf(m - mn) + lo * __expf(mo - mn);
    m = mn;
  }
  float acc = 0.f;
  for (int i = o0 + g; i < o1; i += NG) {
    int v = nidx[i];
    float p = phv[v].x;
    float s = p > 0.f ? p : 0.2f * p;
    float ex = __expf(s - m);
    float hv = (t < D) ? h[(size_t)v * D + t] : 0.f;
    acc += ex * hv;
  }
#pragma unroll
  for (int d = GROUP; d < 64; d <<= 1) acc += __shfl_xor(acc, d);
  float val = acc / (l + 1e-9f);
  float pa = (t < D) ? val * a2[D + t] : 0.f;
#pragma unroll
  for (int d = 1; d < GROUP; d <<= 1) pa += __shfl_xor(pa, d);
  if (g == 0) {
    if (t < D) eout[(size_t)wave * D + t] = val;
    if (t == 0) pe[wave] = pa;
  }
}

// ---------------- node phase ----------------
template <int D, int GROUP>
__global__ void node_phase(const float2* __restrict__ phv, const float* __restrict__ eoutv,
                           const float* __restrict__ pe, const int* __restrict__ noff,
                           const int* __restrict__ perm_e, float* __restrict__ out, int N) {
  constexpr int NG = 64 / GROUP;
  int wave = (blockIdx.x * blockDim.x + threadIdx.x) >> 6;
  int lane = threadIdx.x & 63;
  if (wave >= N) return;
  int o0 = noff[wave], o1 = noff[wave + 1];
  int g = lane / GROUP, t = lane % GROUP;
  if (o0 == o1) {
    if (g == 0 && t < D) out[(size_t)wave * D + t] = 0.f;
    return;
  }
  float ph = phv[wave].y;
  float m = -1e30f, l = 0.f;
  for (int i = o0 + lane; i < o1; i += 64) {
    float p = ph + pe[perm_e[i]];
    float s = p > 0.f ? p : 0.2f * p;
    float mn = fmaxf(m, s);
    l = l * __expf(m - mn) + __expf(s - mn);
    m = mn;
  }
#pragma unroll
  for (int d = 1; d < 64; d <<= 1) {
    float mo = __shfl_xor(m, d), lo = __shfl_xor(l, d);
    float mn = fmaxf(m, mo);
    l = l * __expf(m - mn) + lo * __expf(mo - mn);
    m = mn;
  }
  float acc = 0.f;
  for (int i = o0 + g; i < o1; i += NG) {
    int e = perm_e[i];
    float p = ph + pe[e];
    float s = p > 0.f ? p : 0.2f * p;
    float ex = __expf(s - m);
    float ev = (t < D) ? eoutv[(size_t)e * D + t] : 0.f;
    acc += ex * ev;
  }
#pragma unroll
  for (int d = GROUP; d < 64; d <<= 1) acc += __shfl_xor(acc, d);
  if (g == 0 && t < D) out[(size_t)wave * D + t] = acc / (l + 1e-9f);
}

// ---------------- log_softmax over 7 classes ----------------
__global__ void logsm_kernel(const float* __restrict__ H2, float* __restrict__ logp, int N) {
  int v = blockIdx.x * blockDim.x + threadIdx.x;
  if (v >= N) return;
  float x[N_CLS];
#pragma unroll
  for (int j = 0; j < N_CLS; ++j) x[j] = H2[(size_t)v * N_CLS + j];
  float m = x[0];
#pragma unroll
  for (int j = 1; j < N_CLS; ++j) m = fmaxf(m, x[j]);
  float s = 0.f;
#pragma unroll
  for (int j = 0; j < N_CLS; ++j) s += __expf(x[j] - m);
  float l = logf(s);
#pragma unroll
  for (int j = 0; j < N_CLS; ++j) logp[(size_t)v * N_CLS + j] = x[j] - m - l;
}

// ---------------- launch ----------------

extern "C" void kernel_launch(void* const* d_in, const int* in_sizes, int n_in,
                              void* d_out, int out_size, void* d_ws, size_t ws_size,
                              hipStream_t stream) {
  const float* H    = (const float*)d_in[0];
  const float* W1   = (const float*)d_in[1];
  const float* a1_1 = (const float*)d_in[2];
  const float* a2_1 = (const float*)d_in[3];
  const float* W2   = (const float*)d_in[4];
  const float* a1_2 = (const float*)d_in[5];
  const float* a2_2 = (const float*)d_in[6];
  const int* nidx   = (const int*)d_in[7];
  const int* eidx   = (const int*)d_in[8];

  float* outp = (float*)d_out;
  float* logp = outp;                                   // [N,7]
  float* H1   = outp + (size_t)N_NODES * N_CLS;         // [N,16]
  float* H2   = H1 + (size_t)N_NODES * D_HID;           // [N,7]

  char* ws = (char*)d_ws;
  // binned (12.8 MB) aliases h1g+e1: dead before gemm1 writes h1g.
  int*   binned = (int*)(ws + 0);
  float* h1g  = (float*)(ws + 0);          //  6,400,000 B : N x 16
  float* e1   = (float*)(ws + 6400000);    //  6,400,000 B : E x 16
  float* h2g  = (float*)(ws + 12800000);   //  2,800,000 B : N x 7
  float* e2   = (float*)(ws + 15600000);   //  2,800,000 B : E x 7
  int* eoff   = (int*)(ws + 18400000);     //    400,004 B : E+1
  int* noff   = (int*)(ws + 18800128);     //    400,004 B : N+1
  float* pe   = (float*)(ws + 19200256);   //    400,000 B : E
  int* perm_e = (int*)(ws + 19600384);     // 12,800,000 B : NNZ (edge ids, node-CSR order)
  float2* phv = (float2*)(ws + 32400384);  //    800,000 B : N x {p_a1, p_a2}
  int* gcnt   = (int*)(ws + 33200384);     //      3,128 B : NBK
  int* boff   = (int*)(ws + 33203584);     //      3,132 B : NBK+1
  int* bcur   = (int*)(ws + 33206784);     //      3,128 B : NBK

  const int TB = 256;
  const int nnz_blocks = (NNZ_C + TB - 1) / TB;

  // CSR build (two-level binning; no global scan, no random-line scatter)
  hipMemsetAsync(gcnt, 0, NBK * sizeof(int), stream);
  eoff_kernel<<<nnz_blocks, TB, 0, stream>>>(eidx, eoff, NNZ_C, N_EDGESC);
  hist_kernel<<<250, TB, 0, stream>>>(nidx, gcnt, NNZ_C);
  bscan_kernel<<<1, 1024, 0, stream>>>(gcnt, boff, bcur);
  bin_kernel<<<250, TB, 0, stream>>>(nidx, eidx, bcur, binned, NNZ_C);
  csr_kernel<<<NBK, TB, 0, stream>>>(binned, boff, noff, perm_e, N_NODES);

  // layer 1 (D=16)
  gemm1_kernel<<<(N_NODES + 63) / 64, 64, 0, stream>>>(H, W1, a1_1, a2_1, h1g, phv, N_NODES);
  edge_phase<D_HID, 16><<<(N_EDGESC + 3) / 4, TB, 0, stream>>>(h1g, phv, a2_1, eoff, nidx, e1, pe, N_EDGESC);
  node_phase<D_HID, 16><<<(N_NODES + 3) / 4, TB, 0, stream>>>(phv, e1, pe, noff, perm_e, H1, N_NODES);

  // layer 2 (D=7)
  gemm2_kernel<<<(N_NODES + TB - 1) / TB, TB, 0, stream>>>(H1, W2, a1_2, a2_2, h2g, phv, N_NODES);
  edge_phase<N_CLS, 8><<<(N_EDGESC + 3) / 4, TB, 0, stream>>>(h2g, phv, a2_2, eoff, nidx, e2, pe, N_EDGESC);
  node_phase<N_CLS, 8><<<(N_NODES + 3) / 4, TB, 0, stream>>>(phv, e2, pe, noff, perm_e, H2, N_NODES);

  logsm_kernel<<<(N_NODES + TB - 1) / TB, TB, 0, stream>>>(H2, logp, N_NODES);
}

// Round 5
// 747.055 us; speedup vs baseline: 1.0491x; 1.0491x over previous
//
#include <hip/hip_runtime.h>
#include <hip/hip_bf16.h>
#include <math.h>

#define N_NODES 100000
#define N_EDGESC 100000
#define NNZ_C   3200000
#define D_IN    512
#define D_HID   16
#define N_CLS   7
#define NBK     782   // ceil(100000/128) node buckets, bucket = v>>7

typedef short short8 __attribute__((ext_vector_type(8)));
typedef float f32x4  __attribute__((ext_vector_type(4)));

__device__ __forceinline__ unsigned short f2bf_rn(float x) {
  unsigned int u = __float_as_uint(x);
  u += 0x7fff + ((u >> 16) & 1);
  return (unsigned short)(u >> 16);
}
__device__ __forceinline__ float bf2f(unsigned short b) {
  return __uint_as_float(((unsigned int)b) << 16);
}

// ---------------- setup: eoff from sorted eidx ----------------
__global__ void eoff_kernel(const int* __restrict__ eidx, int* __restrict__ eoff, int nnz, int E) {
  int i = blockIdx.x * blockDim.x + threadIdx.x;
  if (i >= nnz) return;
  int ec = eidx[i];
  int ep = (i == 0) ? -1 : eidx[i - 1];
  for (int e = ep + 1; e <= ec; ++e) eoff[e] = i;
  if (i == nnz - 1) {
    for (int e = ec + 1; e <= E; ++e) eoff[e] = nnz;
  }
}

// ---------------- setup: bucket histogram (LDS-staged) ----------------
__global__ void hist_kernel(const int* __restrict__ nidx, int* __restrict__ gcnt, int nnz) {
  __shared__ int lh[NBK];
  int t = threadIdx.x;
  for (int i = t; i < NBK; i += 256) lh[i] = 0;
  __syncthreads();
  int base = blockIdx.x * 12800;
  for (int it = 0; it < 50; ++it) {
    int i = base + it * 256 + t;
    if (i < nnz) atomicAdd(&lh[nidx[i] >> 7], 1);
  }
  __syncthreads();
  for (int i = t; i < NBK; i += 256) {
    int c = lh[i];
    if (c) atomicAdd(&gcnt[i], c);
  }
}

// ---------------- setup: scan bucket counts -> boff, init bcur ----------------
__global__ void bscan_kernel(const int* __restrict__ gcnt, int* __restrict__ boff,
                             int* __restrict__ bcur) {
  __shared__ int lds[1024];
  int t = threadIdx.x;
  int v = (t < NBK) ? gcnt[t] : 0;
  lds[t] = v;
  __syncthreads();
  for (int d = 1; d < 1024; d <<= 1) {
    int u = (t >= d) ? lds[t - d] : 0;
    __syncthreads();
    lds[t] += u;
    __syncthreads();
  }
  if (t < NBK) {
    boff[t + 1] = lds[t];
    bcur[t] = lds[t] - v;   // exclusive
  }
  if (t == 0) boff[0] = 0;
}

// ---------------- setup: bin entries (packed e | (v&127)<<20) per bucket ----------------
__global__ void bin_kernel(const int* __restrict__ nidx, const int* __restrict__ eidx,
                           int* __restrict__ bcur, int* __restrict__ binned, int nnz) {
  __shared__ int lh[NBK];
  __shared__ int gb[NBK];
  int t = threadIdx.x;
  for (int i = t; i < NBK; i += 256) lh[i] = 0;
  __syncthreads();
  int base = blockIdx.x * 12800;
  for (int it = 0; it < 50; ++it) {
    int i = base + it * 256 + t;
    if (i < nnz) atomicAdd(&lh[nidx[i] >> 7], 1);
  }
  __syncthreads();
  for (int i = t; i < NBK; i += 256) {
    int c = lh[i];
    gb[i] = c ? atomicAdd(&bcur[i], c) : 0;
    lh[i] = 0;
  }
  __syncthreads();
  for (int it = 0; it < 50; ++it) {
    int i = base + it * 256 + t;
    if (i < nnz) {
      int v = nidx[i], e = eidx[i];
      int bk = v >> 7;
      int r = atomicAdd(&lh[bk], 1);
      binned[gb[bk] + r] = e | ((v & 127) << 20);
    }
  }
}

// ---------------- setup: per-bucket node-CSR (noff + perm_e) ----------------
__global__ void csr_kernel(const int* __restrict__ binned, const int* __restrict__ boff,
                           int* __restrict__ noff, int* __restrict__ perm_e, int N) {
  __shared__ int lh[128];
  __shared__ int lsc[128];
  __shared__ int lcur[128];
  int b = blockIdx.x;
  int t = threadIdx.x;
  int s = boff[b], e = boff[b + 1];
  if (t < 128) lh[t] = 0;
  __syncthreads();
  for (int i = s + t; i < e; i += 256) {
    atomicAdd(&lh[binned[i] >> 20], 1);
  }
  __syncthreads();
  if (t < 128) lsc[t] = lh[t];
  __syncthreads();
  for (int d = 1; d < 128; d <<= 1) {
    int u = (t < 128 && t >= d) ? lsc[t - d] : 0;
    __syncthreads();
    if (t < 128) lsc[t] += u;
    __syncthreads();
  }
  if (t < 128) {
    int excl = lsc[t] - lh[t];
    lcur[t] = excl;
    int n = b * 128 + t;
    if (n <= N) noff[n] = s + excl;
  }
  __syncthreads();
  for (int i = s + t; i < e; i += 256) {
    int p = binned[i];
    int r = atomicAdd(&lcur[p >> 20], 1);
    perm_e[s + r] = p & 0xFFFFF;
  }
}

// ---------------- GEMM1 via MFMA (bf16 3-term split): h = X @ W1  (+ phv epilogue) ----
// 1 wave per 16-row tile; A-frag A[m=lane&15][k=quad*8+j]; W frags (hi+lo) in VGPRs for
// all 16 k-chunks; 3 independent accumulators; C-layout col=lane&15,row=quad*4+reg.
__global__ __launch_bounds__(256) void gemm1_kernel(
    const float* __restrict__ X, const float* __restrict__ W,
    const float* __restrict__ a1, const float* __restrict__ a2,
    float* __restrict__ Hout, float2* __restrict__ phv, int numTiles) {
  int wid = blockIdx.x * 4 + (threadIdx.x >> 6);
  if (wid >= numTiles) return;
  int lane = threadIdx.x & 63;
  int col  = lane & 15;
  int quad = lane >> 4;

  // B fragments for all 16 k-chunks (hi+lo), held in registers
  short8 wh[16], wl[16];
#pragma unroll
  for (int c = 0; c < 16; ++c) {
#pragma unroll
    for (int j = 0; j < 8; ++j) {
      float w = W[(c * 32 + quad * 8 + j) * 16 + col];
      unsigned short h = f2bf_rn(w);
      wh[c][j] = (short)h;
      wl[c][j] = (short)f2bf_rn(w - bf2f(h));
    }
  }

  int rowbase = wid * 16;
  const float4* Xr = (const float4*)(X + (size_t)(rowbase + col) * D_IN) + quad * 2;
  // Xr[c*8], Xr[c*8+1] cover k-chunk c for this lane (32 B, fully used lines).

  f32x4 acc_hh = {0.f, 0.f, 0.f, 0.f};
  f32x4 acc_hl = {0.f, 0.f, 0.f, 0.f};
  f32x4 acc_lh = {0.f, 0.f, 0.f, 0.f};

  float4 u0 = Xr[0], u1 = Xr[1];
#pragma unroll
  for (int c = 0; c < 16; ++c) {
    float4 n0, n1;
    if (c < 15) { n0 = Xr[(c + 1) * 8]; n1 = Xr[(c + 1) * 8 + 1]; }
    float xs[8] = {u0.x, u0.y, u0.z, u0.w, u1.x, u1.y, u1.z, u1.w};
    short8 ah, al;
#pragma unroll
    for (int j = 0; j < 8; ++j) {
      unsigned short h = f2bf_rn(xs[j]);
      ah[j] = (short)h;
      al[j] = (short)f2bf_rn(xs[j] - bf2f(h));
    }
    acc_hh = __builtin_amdgcn_mfma_f32_16x16x32_bf16(ah, wh[c], acc_hh, 0, 0, 0);
    acc_hl = __builtin_amdgcn_mfma_f32_16x16x32_bf16(ah, wl[c], acc_hl, 0, 0, 0);
    acc_lh = __builtin_amdgcn_mfma_f32_16x16x32_bf16(al, wh[c], acc_lh, 0, 0, 0);
    u0 = n0; u1 = n1;
  }

  float a1c = a1[col], a2c = a2[col];
#pragma unroll
  for (int r = 0; r < 4; ++r) {
    float v = acc_hh[r] + acc_hl[r] + acc_lh[r];
    int row = rowbase + quad * 4 + r;
    Hout[(size_t)row * 16 + col] = v;
    float p1 = v * a1c, p2 = v * a2c;
#pragma unroll
    for (int d = 1; d < 16; d <<= 1) { p1 += __shfl_xor(p1, d); p2 += __shfl_xor(p2, d); }
    if (col == 0) phv[row] = make_float2(p1, p2);
  }
}

// ---------------- GEMM2: h2 = elu(H1)[100000,16] @ W2[16,7] (+ phv epilogue) ----------------
__global__ void gemm2_kernel(const float* __restrict__ H1, const float* __restrict__ W2,
                             const float* __restrict__ a1, const float* __restrict__ a2,
                             float* __restrict__ h2, float2* __restrict__ phv, int N) {
  __shared__ float w[D_HID * N_CLS];
  if (threadIdx.x < D_HID * N_CLS) w[threadIdx.x] = W2[threadIdx.x];
  __syncthreads();
  int v = blockIdx.x * blockDim.x + threadIdx.x;
  if (v >= N) return;
  const float4* h4 = (const float4*)(H1 + (size_t)v * D_HID);
  float x[16];
#pragma unroll
  for (int q = 0; q < 4; ++q) {
    float4 f = h4[q];
    x[q * 4 + 0] = f.x; x[q * 4 + 1] = f.y; x[q * 4 + 2] = f.z; x[q * 4 + 3] = f.w;
  }
#pragma unroll
  for (int k = 0; k < 16; ++k) x[k] = x[k] > 0.f ? x[k] : expm1f(x[k]);
  float p1 = 0.f, p2 = 0.f;
#pragma unroll
  for (int jj = 0; jj < N_CLS; ++jj) {
    float acc = 0.f;
#pragma unroll
    for (int k = 0; k < 16; ++k) acc += x[k] * w[k * N_CLS + jj];
    h2[(size_t)v * N_CLS + jj] = acc;
    p1 += acc * a1[jj];
    p2 += acc * a2[jj];
  }
  phv[v] = make_float2(p1, p2);
}

// ---------------- edge phase ----------------
template <int D, int GROUP>
__global__ void edge_phase(const float* __restrict__ h, const float2* __restrict__ phv,
                           const float* __restrict__ a2,
                           const int* __restrict__ eoff, const int* __restrict__ nidx,
                           float* __restrict__ eout, float* __restrict__ pe, int E) {
  constexpr int NG = 64 / GROUP;
  int wave = (blockIdx.x * blockDim.x + threadIdx.x) >> 6;
  int lane = threadIdx.x & 63;
  if (wave >= E) return;
  int o0 = eoff[wave], o1 = eoff[wave + 1];
  int g = lane / GROUP, t = lane % GROUP;
  if (o0 == o1) {
    if (g == 0 && t < D) eout[(size_t)wave * D + t] = 0.f;
    if (lane == 0) pe[wave] = 0.f;
    return;
  }
  float m = -1e30f, l = 0.f;
  for (int i = o0 + lane; i < o1; i += 64) {
    float p = phv[nidx[i]].x;
    float s = p > 0.f ? p : 0.2f * p;
    float mn = fmaxf(m, s);
    l = l * __expf(m - mn) + __expf(s - mn);
    m = mn;
  }
#pragma unroll
  for (int d = 1; d < 64; d <<= 1) {
    float mo = __shfl_xor(m, d), lo = __shfl_xor(l, d);
    float mn = fmaxf(m, mo);
    l = l * __expf(m - mn) + lo * __expf(mo - mn);
    m = mn;
  }
  float acc = 0.f;
  for (int i = o0 + g; i < o1; i += NG) {
    int v = nidx[i];
    float p = phv[v].x;
    float s = p > 0.f ? p : 0.2f * p;
    float ex = __expf(s - m);
    float hv = (t < D) ? h[(size_t)v * D + t] : 0.f;
    acc += ex * hv;
  }
#pragma unroll
  for (int d = GROUP; d < 64; d <<= 1) acc += __shfl_xor(acc, d);
  float val = acc / (l + 1e-9f);
  float pa = (t < D) ? val * a2[D + t] : 0.f;
#pragma unroll
  for (int d = 1; d < GROUP; d <<= 1) pa += __shfl_xor(pa, d);
  if (g == 0) {
    if (t < D) eout[(size_t)wave * D + t] = val;
    if (t == 0) pe[wave] = pa;
  }
}

// ---------------- node phase ----------------
template <int D, int GROUP>
__global__ void node_phase(const float2* __restrict__ phv, const float* __restrict__ eoutv,
                           const float* __restrict__ pe, const int* __restrict__ noff,
                           const int* __restrict__ perm_e, float* __restrict__ out, int N) {
  constexpr int NG = 64 / GROUP;
  int wave = (blockIdx.x * blockDim.x + threadIdx.x) >> 6;
  int lane = threadIdx.x & 63;
  if (wave >= N) return;
  int o0 = noff[wave], o1 = noff[wave + 1];
  int g = lane / GROUP, t = lane % GROUP;
  if (o0 == o1) {
    if (g == 0 && t < D) out[(size_t)wave * D + t] = 0.f;
    return;
  }
  float ph = phv[wave].y;
  float m = -1e30f, l = 0.f;
  for (int i = o0 + lane; i < o1; i += 64) {
    float p = ph + pe[perm_e[i]];
    float s = p > 0.f ? p : 0.2f * p;
    float mn = fmaxf(m, s);
    l = l * __expf(m - mn) + __expf(s - mn);
    m = mn;
  }
#pragma unroll
  for (int d = 1; d < 64; d <<= 1) {
    float mo = __shfl_xor(m, d), lo = __shfl_xor(l, d);
    float mn = fmaxf(m, mo);
    l = l * __expf(m - mn) + lo * __expf(mo - mn);
    m = mn;
  }
  float acc = 0.f;
  for (int i = o0 + g; i < o1; i += NG) {
    int e = perm_e[i];
    float p = ph + pe[e];
    float s = p > 0.f ? p : 0.2f * p;
    float ex = __expf(s - m);
    float ev = (t < D) ? eoutv[(size_t)e * D + t] : 0.f;
    acc += ex * ev;
  }
#pragma unroll
  for (int d = GROUP; d < 64; d <<= 1) acc += __shfl_xor(acc, d);
  if (g == 0 && t < D) out[(size_t)wave * D + t] = acc / (l + 1e-9f);
}

// ---------------- log_softmax over 7 classes ----------------
__global__ void logsm_kernel(const float* __restrict__ H2, float* __restrict__ logp, int N) {
  int v = blockIdx.x * blockDim.x + threadIdx.x;
  if (v >= N) return;
  float x[N_CLS];
#pragma unroll
  for (int j = 0; j < N_CLS; ++j) x[j] = H2[(size_t)v * N_CLS + j];
  float m = x[0];
#pragma unroll
  for (int j = 1; j < N_CLS; ++j) m = fmaxf(m, x[j]);
  float s = 0.f;
#pragma unroll
  for (int j = 0; j < N_CLS; ++j) s += __expf(x[j] - m);
  float l = logf(s);
#pragma unroll
  for (int j = 0; j < N_CLS; ++j) logp[(size_t)v * N_CLS + j] = x[j] - m - l;
}

// ---------------- launch ----------------

extern "C" void kernel_launch(void* const* d_in, const int* in_sizes, int n_in,
                              void* d_out, int out_size, void* d_ws, size_t ws_size,
                              hipStream_t stream) {
  const float* H    = (const float*)d_in[0];
  const float* W1   = (const float*)d_in[1];
  const float* a1_1 = (const float*)d_in[2];
  const float* a2_1 = (const float*)d_in[3];
  const float* W2   = (const float*)d_in[4];
  const float* a1_2 = (const float*)d_in[5];
  const float* a2_2 = (const float*)d_in[6];
  const int* nidx   = (const int*)d_in[7];
  const int* eidx   = (const int*)d_in[8];

  float* outp = (float*)d_out;
  float* logp = outp;                                   // [N,7]
  float* H1   = outp + (size_t)N_NODES * N_CLS;         // [N,16]
  float* H2   = H1 + (size_t)N_NODES * D_HID;           // [N,7]

  char* ws = (char*)d_ws;
  // binned (12.8 MB) aliases h1g+e1: dead before gemm1 writes h1g.
  int*   binned = (int*)(ws + 0);
  float* h1g  = (float*)(ws + 0);          //  6,400,000 B : N x 16
  float* e1   = (float*)(ws + 6400000);    //  6,400,000 B : E x 16
  float* h2g  = (float*)(ws + 12800000);   //  2,800,000 B : N x 7
  float* e2   = (float*)(ws + 15600000);   //  2,800,000 B : E x 7
  int* eoff   = (int*)(ws + 18400000);     //    400,004 B : E+1
  int* noff   = (int*)(ws + 18800128);     //    400,004 B : N+1
  float* pe   = (float*)(ws + 19200256);   //    400,000 B : E
  int* perm_e = (int*)(ws + 19600384);     // 12,800,000 B : NNZ (edge ids, node-CSR order)
  float2* phv = (float2*)(ws + 32400384);  //    800,000 B : N x {p_a1, p_a2}
  int* gcnt   = (int*)(ws + 33200384);     //      3,128 B : NBK
  int* boff   = (int*)(ws + 33203584);     //      3,132 B : NBK+1
  int* bcur   = (int*)(ws + 33206784);     //      3,128 B : NBK

  const int TB = 256;
  const int nnz_blocks = (NNZ_C + TB - 1) / TB;

  // CSR build (two-level binning; no global scan, no random-line scatter)
  hipMemsetAsync(gcnt, 0, NBK * sizeof(int), stream);
  eoff_kernel<<<nnz_blocks, TB, 0, stream>>>(eidx, eoff, NNZ_C, N_EDGESC);
  hist_kernel<<<250, TB, 0, stream>>>(nidx, gcnt, NNZ_C);
  bscan_kernel<<<1, 1024, 0, stream>>>(gcnt, boff, bcur);
  bin_kernel<<<250, TB, 0, stream>>>(nidx, eidx, bcur, binned, NNZ_C);
  csr_kernel<<<NBK, TB, 0, stream>>>(binned, boff, noff, perm_e, N_NODES);

  // layer 1 (D=16): MFMA GEMM, 16 rows per wave
  {
    const int TILES = (N_NODES + 15) / 16;   // 6250
    gemm1_kernel<<<(TILES + 3) / 4, TB, 0, stream>>>(H, W1, a1_1, a2_1, h1g, phv, TILES);
  }
  edge_phase<D_HID, 16><<<(N_EDGESC + 3) / 4, TB, 0, stream>>>(h1g, phv, a2_1, eoff, nidx, e1, pe, N_EDGESC);
  node_phase<D_HID, 16><<<(N_NODES + 3) / 4, TB, 0, stream>>>(phv, e1, pe, noff, perm_e, H1, N_NODES);

  // layer 2 (D=7)
  gemm2_kernel<<<(N_NODES + TB - 1) / TB, TB, 0, stream>>>(H1, W2, a1_2, a2_2, h2g, phv, N_NODES);
  edge_phase<N_CLS, 8><<<(N_EDGESC + 3) / 4, TB, 0, stream>>>(h2g, phv, a2_2, eoff, nidx, e2, pe, N_EDGESC);
  node_phase<N_CLS, 8><<<(N_NODES + 3) / 4, TB, 0, stream>>>(phv, e2, pe, noff, perm_e, H2, N_NODES);

  logsm_kernel<<<(N_NODES + TB - 1) / TB, TB, 0, stream>>>(H2, logp, N_NODES);
}